// Round 1
// baseline (96.815 us; speedup 1.0000x reference)
//
#include <hip/hip_runtime.h>

#define P 128
#define BLOCK 256
#define RPT 4                 // consecutive outputs per thread
#define TILE (BLOCK * RPT)    // 1024 outputs per block
#define STAGE (TILE + P)      // 1152 floats of y staged per block

// FIR/AR prediction: pred[i] = sum_j y[i+j]*params[j], i in [0, n)
// plus partial sum of (pred[i] - y[i+P])^2 into loss_acc (atomic per block).
__global__ __launch_bounds__(BLOCK) void ar_pred_kernel(
    const float* __restrict__ y, const float* __restrict__ params,
    float* __restrict__ out, float* __restrict__ loss_acc,
    int n, int Ntot)
{
    __shared__ float ylds[STAGE];
    __shared__ float plds[P];
    __shared__ float red[BLOCK / 64];

    const int t = threadIdx.x;
    const int tile0 = blockIdx.x * TILE;

    // stage params (tiny, broadcast-read later)
    if (t < P) plds[t] = params[t];

    // stage y tile: vector path when fully in range, guarded scalar otherwise
    if (tile0 + STAGE <= Ntot) {
        const float4* src = (const float4*)(y + tile0);  // tile0 % 1024 == 0 -> 16B aligned
        float4* dst = (float4*)ylds;
        dst[t] = src[t];
        if (t < STAGE / 4 - BLOCK) dst[t + BLOCK] = src[t + BLOCK];
    } else {
        for (int idx = t; idx < STAGE; idx += BLOCK) {
            int g = tile0 + idx;
            ylds[idx] = (g < Ntot) ? y[g] : 0.f;
        }
    }
    __syncthreads();

    // register sliding window: 4 consecutive outputs/thread,
    // per 4 taps: 1 ds_read_b128 (y) + 1 ds_read_b128 (params bcast) + 16 FMA
    const int l0 = t * RPT;                 // 16B-aligned LDS float index
    float4 w0 = *(const float4*)&ylds[l0];  // y[i0 .. i0+3]
    float a0 = 0.f, a1 = 0.f, a2 = 0.f, a3 = 0.f;
    #pragma unroll
    for (int j = 0; j < P; j += 4) {
        float4 w1 = *(const float4*)&ylds[l0 + j + 4];
        float4 pj = *(const float4*)&plds[j];
        // tap j+0: y[i0+j+0+k]
        a0 = fmaf(w0.x, pj.x, a0); a1 = fmaf(w0.y, pj.x, a1);
        a2 = fmaf(w0.z, pj.x, a2); a3 = fmaf(w0.w, pj.x, a3);
        // tap j+1
        a0 = fmaf(w0.y, pj.y, a0); a1 = fmaf(w0.z, pj.y, a1);
        a2 = fmaf(w0.w, pj.y, a2); a3 = fmaf(w1.x, pj.y, a3);
        // tap j+2
        a0 = fmaf(w0.z, pj.z, a0); a1 = fmaf(w0.w, pj.z, a1);
        a2 = fmaf(w1.x, pj.z, a2); a3 = fmaf(w1.y, pj.z, a3);
        // tap j+3
        a0 = fmaf(w0.w, pj.w, a0); a1 = fmaf(w1.x, pj.w, a1);
        a2 = fmaf(w1.y, pj.w, a2); a3 = fmaf(w1.z, pj.w, a3);
        w0 = w1;
    }

    const int i0 = tile0 + l0;
    float sq = 0.f;
    if (i0 < n) {  // n and i0 both multiples of 4 -> all 4 outputs valid
        float r0 = a0 - ylds[l0 + 0 + P];
        float r1 = a1 - ylds[l0 + 1 + P];
        float r2 = a2 - ylds[l0 + 2 + P];
        float r3 = a3 - ylds[l0 + 3 + P];
        sq = r0 * r0 + r1 * r1 + r2 * r2 + r3 * r3;
        float4 o; o.x = a0; o.y = a1; o.z = a2; o.w = a3;
        *(float4*)(out + i0) = o;
    }

    // wave64 shuffle reduce, then one atomic per block
    #pragma unroll
    for (int off = 32; off >= 1; off >>= 1)
        sq += __shfl_down(sq, off, 64);
    if ((t & 63) == 0) red[t >> 6] = sq;
    __syncthreads();
    if (t == 0) {
        atomicAdd(loss_acc, red[0] + red[1] + red[2] + red[3]);
    }
}

// loss = sq_sum / n + sum(|params|); written to out[n]
__global__ __launch_bounds__(64) void ar_finalize(
    const float* __restrict__ params, const float* __restrict__ loss_acc,
    float* __restrict__ out, int n)
{
    int t = threadIdx.x;  // 64 threads
    float s = fabsf(params[t]) + fabsf(params[t + 64]);
    #pragma unroll
    for (int off = 32; off >= 1; off >>= 1)
        s += __shfl_down(s, off, 64);
    if (t == 0) out[n] = loss_acc[0] / (float)n + s;
}

extern "C" void kernel_launch(void* const* d_in, const int* in_sizes, int n_in,
                              void* d_out, int out_size, void* d_ws, size_t ws_size,
                              hipStream_t stream)
{
    const float* y      = (const float*)d_in[0];
    const float* params = (const float*)d_in[1];
    float* out = (float*)d_out;
    float* acc = (float*)d_ws;

    const int Ntot = in_sizes[0];   // 2,000,128
    const int n    = Ntot - P;      // 2,000,000

    hipMemsetAsync(acc, 0, sizeof(float), stream);  // ws is re-poisoned 0xAA each call

    const int nblocks = (n + TILE - 1) / TILE;      // 1954
    ar_pred_kernel<<<nblocks, BLOCK, 0, stream>>>(y, params, out, acc, n, Ntot);
    ar_finalize<<<1, 64, 0, stream>>>(params, acc, out, n);
}

// Round 2
// 85.194 us; speedup vs baseline: 1.1364x; 1.1364x over previous
//
#include <hip/hip_runtime.h>

#define P 128
#define BLOCK 256
#define RPT 4                 // consecutive outputs per thread
#define TILE (BLOCK * RPT)    // 1024 outputs per block
#define STAGE (TILE + P)      // 1152 floats of y staged per block

// FIR/AR prediction: pred[i] = sum_j y[i+j]*params[j], i in [0, n)
// Each block writes its partial sum of (pred-y)^2 to partials[blockIdx.x]
// (plain store into d_ws -- no init, no atomic contention).
__global__ __launch_bounds__(BLOCK) void ar_pred_kernel(
    const float* __restrict__ y, const float* __restrict__ params,
    float* __restrict__ out, float* __restrict__ partials,
    int n, int Ntot)
{
    __shared__ float ylds[STAGE];
    __shared__ float plds[P];
    __shared__ float red[BLOCK / 64];

    const int t = threadIdx.x;
    const int tile0 = blockIdx.x * TILE;

    // stage params (tiny, broadcast-read later)
    if (t < P) plds[t] = params[t];

    // stage y tile: vector path when fully in range, guarded scalar otherwise
    if (tile0 + STAGE <= Ntot) {
        const float4* src = (const float4*)(y + tile0);  // tile0 % 1024 == 0 -> 16B aligned
        float4* dst = (float4*)ylds;
        dst[t] = src[t];
        if (t < STAGE / 4 - BLOCK) dst[t + BLOCK] = src[t + BLOCK];
    } else {
        for (int idx = t; idx < STAGE; idx += BLOCK) {
            int g = tile0 + idx;
            ylds[idx] = (g < Ntot) ? y[g] : 0.f;
        }
    }
    __syncthreads();

    // register sliding window: 4 consecutive outputs/thread,
    // per 4 taps: 1 ds_read_b128 (y, contiguous 16B/lane) + 1 broadcast + 16 FMA
    const int l0 = t * RPT;                 // 16B-aligned LDS float index
    float4 w0 = *(const float4*)&ylds[l0];  // y[i0 .. i0+3]
    float a0 = 0.f, a1 = 0.f, a2 = 0.f, a3 = 0.f;
    #pragma unroll
    for (int j = 0; j < P; j += 4) {
        float4 w1 = *(const float4*)&ylds[l0 + j + 4];
        float4 pj = *(const float4*)&plds[j];
        // tap j+0
        a0 = fmaf(w0.x, pj.x, a0); a1 = fmaf(w0.y, pj.x, a1);
        a2 = fmaf(w0.z, pj.x, a2); a3 = fmaf(w0.w, pj.x, a3);
        // tap j+1
        a0 = fmaf(w0.y, pj.y, a0); a1 = fmaf(w0.z, pj.y, a1);
        a2 = fmaf(w0.w, pj.y, a2); a3 = fmaf(w1.x, pj.y, a3);
        // tap j+2
        a0 = fmaf(w0.z, pj.z, a0); a1 = fmaf(w0.w, pj.z, a1);
        a2 = fmaf(w1.x, pj.z, a2); a3 = fmaf(w1.y, pj.z, a3);
        // tap j+3
        a0 = fmaf(w0.w, pj.w, a0); a1 = fmaf(w1.x, pj.w, a1);
        a2 = fmaf(w1.y, pj.w, a2); a3 = fmaf(w1.z, pj.w, a3);
        w0 = w1;
    }

    const int i0 = tile0 + l0;
    float sq = 0.f;
    if (i0 < n) {  // n and i0 both multiples of 4 -> all 4 outputs valid
        float r0 = a0 - ylds[l0 + 0 + P];
        float r1 = a1 - ylds[l0 + 1 + P];
        float r2 = a2 - ylds[l0 + 2 + P];
        float r3 = a3 - ylds[l0 + 3 + P];
        sq = r0 * r0 + r1 * r1 + r2 * r2 + r3 * r3;
        float4 o; o.x = a0; o.y = a1; o.z = a2; o.w = a3;
        *(float4*)(out + i0) = o;
    }

    // wave64 shuffle reduce, LDS combine, one plain store per block
    #pragma unroll
    for (int off = 32; off >= 1; off >>= 1)
        sq += __shfl_down(sq, off, 64);
    if ((t & 63) == 0) red[t >> 6] = sq;
    __syncthreads();
    if (t == 0)
        partials[blockIdx.x] = red[0] + red[1] + red[2] + red[3];
}

// loss = (sum partials)/n + sum(|params|); written to out[n]
__global__ __launch_bounds__(256) void ar_finalize(
    const float* __restrict__ params, const float* __restrict__ partials,
    float* __restrict__ out, int n, int nblocks)
{
    __shared__ float redsq[4];
    __shared__ float redl1[4];
    const int t = threadIdx.x;

    float sq = 0.f;
    for (int i = t; i < nblocks; i += 256) sq += partials[i];
    float l1 = (t < P) ? fabsf(params[t]) : 0.f;

    #pragma unroll
    for (int off = 32; off >= 1; off >>= 1) {
        sq += __shfl_down(sq, off, 64);
        l1 += __shfl_down(l1, off, 64);
    }
    if ((t & 63) == 0) { redsq[t >> 6] = sq; redl1[t >> 6] = l1; }
    __syncthreads();
    if (t == 0) {
        float s = redsq[0] + redsq[1] + redsq[2] + redsq[3];
        float a = redl1[0] + redl1[1] + redl1[2] + redl1[3];
        out[n] = s / (float)n + a;
    }
}

extern "C" void kernel_launch(void* const* d_in, const int* in_sizes, int n_in,
                              void* d_out, int out_size, void* d_ws, size_t ws_size,
                              hipStream_t stream)
{
    const float* y      = (const float*)d_in[0];
    const float* params = (const float*)d_in[1];
    float* out      = (float*)d_out;
    float* partials = (float*)d_ws;   // nblocks floats, written before read

    const int Ntot = in_sizes[0];   // 2,000,128
    const int n    = Ntot - P;      // 2,000,000

    const int nblocks = (n + TILE - 1) / TILE;      // 1954
    ar_pred_kernel<<<nblocks, BLOCK, 0, stream>>>(y, params, out, partials, n, Ntot);
    ar_finalize<<<1, 256, 0, stream>>>(params, partials, out, n, nblocks);
}

// Round 5
// 69.452 us; speedup vs baseline: 1.3940x; 1.2267x over previous
//
#include <hip/hip_runtime.h>

#define P 128
#define BLOCK 256
#define RPT 8                    // consecutive outputs per thread
#define TILE (BLOCK * RPT)       // 2048 outputs per block
#define STAGE (TILE + P)         // 2176 floats of y staged per block
#define NSLOT (STAGE / 4)        // 544 float4 slots

// LDS float4-slot swizzle: flip bit0 of slot when bit3 set (== flip byte-bit-4
// on odd 128B rows). Reads at slot-stride 2 (32B) would otherwise use only 16
// of 32 banks (2x serialization); swizzle spreads odd rows onto the other 16.
// Applied on BOTH write and read (reg-staged staging, so both sides legal).
__device__ __forceinline__ int swz(int u) { return u ^ ((u >> 3) & 1); }

// pred[i] = sum_j y[i+j]*params[j]; per-block partial of (pred-y)^2 -> partials.
// params are read via uniform scalar loads (s_load -> SGPR FMA operands),
// y tile staged in swizzled LDS, 8 outputs/thread register sliding window.
__global__ __launch_bounds__(BLOCK) void ar_pred_kernel(
    const float* __restrict__ y, const float* __restrict__ params,
    float* __restrict__ out, float* __restrict__ partials,
    int n, int Ntot)
{
    __shared__ float4 ylds[NSLOT];
    __shared__ float red[BLOCK / 64];

    const int t = threadIdx.x;
    const int tile0 = blockIdx.x * TILE;

    if (tile0 + STAGE <= Ntot) {
        const float4* src = (const float4*)(y + tile0);  // tile0 % 2048 == 0 -> aligned
        ylds[swz(t)]       = src[t];
        ylds[swz(t + 256)] = src[t + 256];
        if (t < NSLOT - 512) ylds[swz(t + 512)] = src[t + 512];
    } else {
        float* yl = (float*)ylds;
        for (int idx = t; idx < STAGE; idx += BLOCK) {
            int g = tile0 + idx;
            yl[idx ^ (((idx >> 5) & 1) << 2)] = (g < Ntot) ? y[g] : 0.f;
        }
    }
    __syncthreads();

    const int base  = t * RPT;      // float index of first output's window
    const int ubase = base >> 2;    // float4 slot index (even)

    // sliding window wv[0..11]: y[base+j .. base+j+11]; all indices below are
    // unroll-constant -> SROA to registers (no scratch).
    float wv[12];
    {
        float4 a = ylds[swz(ubase)];
        float4 b = ylds[swz(ubase + 1)];
        wv[0] = a.x; wv[1] = a.y; wv[2] = a.z; wv[3] = a.w;
        wv[4] = b.x; wv[5] = b.y; wv[6] = b.z; wv[7] = b.w;
    }
    float acc[RPT];
    #pragma unroll
    for (int m = 0; m < RPT; ++m) acc[m] = 0.f;

    #pragma unroll
    for (int jj = 0; jj < P / 4; ++jj) {
        float4 c = ylds[swz(ubase + 2 + jj)];
        wv[8] = c.x; wv[9] = c.y; wv[10] = c.z; wv[11] = c.w;
        #pragma unroll
        for (int k = 0; k < 4; ++k) {
            const float p = params[jj * 4 + k];   // uniform -> s_load, SGPR operand
            #pragma unroll
            for (int m = 0; m < RPT; ++m)
                acc[m] = fmaf(wv[k + m], p, acc[m]);
        }
        #pragma unroll
        for (int i = 0; i < 8; ++i) wv[i] = wv[i + 4];
    }

    const int i0 = tile0 + base;
    float sq = 0.f;
    if (i0 < n) {   // n - tile0 is a multiple of 8 -> all 8 outputs valid
        float4 t0 = ylds[swz(ubase + 32)];       // y[base+P .. base+P+3]
        float4 t1 = ylds[swz(ubase + 33)];
        float r0 = acc[0] - t0.x, r1 = acc[1] - t0.y;
        float r2 = acc[2] - t0.z, r3 = acc[3] - t0.w;
        float r4 = acc[4] - t1.x, r5 = acc[5] - t1.y;
        float r6 = acc[6] - t1.z, r7 = acc[7] - t1.w;
        sq = r0*r0 + r1*r1 + r2*r2 + r3*r3 + r4*r4 + r5*r5 + r6*r6 + r7*r7;
        float4 o0; o0.x = acc[0]; o0.y = acc[1]; o0.z = acc[2]; o0.w = acc[3];
        float4 o1; o1.x = acc[4]; o1.y = acc[5]; o1.z = acc[6]; o1.w = acc[7];
        *(float4*)(out + i0)     = o0;
        *(float4*)(out + i0 + 4) = o1;
    }

    // wave64 shuffle reduce, LDS combine, one plain store per block
    #pragma unroll
    for (int off = 32; off >= 1; off >>= 1)
        sq += __shfl_down(sq, off, 64);
    if ((t & 63) == 0) red[t >> 6] = sq;
    __syncthreads();
    if (t == 0)
        partials[blockIdx.x] = red[0] + red[1] + red[2] + red[3];
}

// loss = (sum partials)/n + sum(|params|); written to out[n]
__global__ __launch_bounds__(256) void ar_finalize(
    const float* __restrict__ params, const float* __restrict__ partials,
    float* __restrict__ out, int n, int nblocks)
{
    __shared__ float redsq[4];
    __shared__ float redl1[4];
    const int t = threadIdx.x;

    float sq = 0.f;
    for (int i = t; i < nblocks; i += 256) sq += partials[i];
    float l1 = (t < P) ? fabsf(params[t]) : 0.f;

    #pragma unroll
    for (int off = 32; off >= 1; off >>= 1) {
        sq += __shfl_down(sq, off, 64);
        l1 += __shfl_down(l1, off, 64);
    }
    if ((t & 63) == 0) { redsq[t >> 6] = sq; redl1[t >> 6] = l1; }
    __syncthreads();
    if (t == 0) {
        float s = redsq[0] + redsq[1] + redsq[2] + redsq[3];
        float a = redl1[0] + redl1[1] + redl1[2] + redl1[3];
        out[n] = s / (float)n + a;
    }
}

extern "C" void kernel_launch(void* const* d_in, const int* in_sizes, int n_in,
                              void* d_out, int out_size, void* d_ws, size_t ws_size,
                              hipStream_t stream)
{
    const float* y      = (const float*)d_in[0];
    const float* params = (const float*)d_in[1];
    float* out      = (float*)d_out;
    float* partials = (float*)d_ws;   // nblocks floats, written before read

    const int Ntot = in_sizes[0];   // 2,000,128
    const int n    = Ntot - P;      // 2,000,000

    const int nblocks = (n + TILE - 1) / TILE;      // 977
    ar_pred_kernel<<<nblocks, BLOCK, 0, stream>>>(y, params, out, partials, n, Ntot);
    ar_finalize<<<1, 256, 0, stream>>>(params, partials, out, n, nblocks);
}